// Round 15
// baseline (400.031 us; speedup 1.0000x reference)
//
#include <hip/hip_runtime.h>
#include <hip/hip_bf16.h>

typedef unsigned short u16;
typedef unsigned int   u32;
typedef __attribute__((ext_vector_type(8))) short bf16x8;
typedef __attribute__((ext_vector_type(4))) float f32x4;

#define NB 8192

__device__ __forceinline__ u32 pack2bf(float a, float b) {
    __hip_bfloat162 h = __float22bfloat162_rn(make_float2(a, b));  // v_cvt_pk_bf16_f32
    return *reinterpret_cast<u32*>(&h);
}

__device__ __forceinline__ u16 f2bf(float x) {
    u32 u = __float_as_uint(x);
    u32 r = u + 0x7FFFu + ((u >> 16) & 1u);
    return (u16)(r >> 16);
}

// Fragment-linear weight layouts — IDENTICAL to R7 (proven):
//   w1fr: frag f = m*4 + ks (m=0..15)   elem(l,j): W1[d][c], d=32ks+8*(l>>4)+j, c=16m+(l&15)
//   w2fr: frag f = t*8 + ks (t=0..15)   elem(l,j): W2[c][e], c=32ks+8*(l>>4)+j, e=16t+(l&15)
__global__ __launch_bounds__(256) void prep_weights(
    const float* __restrict__ W1, const float* __restrict__ W2,
    u16* __restrict__ w1fr, u16* __restrict__ w2fr)
{
    int tid = blockIdx.x * 256 + threadIdx.x;
    if (tid < 32768) {
        const int f = tid >> 9, r = tid & 511, l = r >> 3, j = r & 7;
        const int m = f >> 2, ks = f & 3;
        const int c = 16 * m + (l & 15);
        const int d = 32 * ks + 8 * (l >> 4) + j;
        w1fr[tid] = f2bf(W1[d * 256 + c]);
    } else {
        const int t2 = tid - 32768;
        if (t2 < 65536) {
            const int f = t2 >> 9, r = t2 & 511, l = r >> 3, j = r & 7;
            const int t = f >> 3, ks = f & 7;
            const int e = 16 * t + (l & 15);
            const int c = 32 * ks + 8 * (l >> 4) + j;
            w2fr[t2] = f2bf(W2[c * 256 + e]);
        }
    }
}

// ZERO-BARRIER kernel: one block = one batch, 4 waves; wave w owns rows
// n in [16w,16w+16) end-to-end. Each wave: stage own X^T-slice -> private
// 8KB LDS region | L1 (A=full W1, 16 tiles; B=own xt rows) | ep1 -> own h1
// slice (same region, in-wave RAW) | L2 (A=own h1 rows, B=full W2) |
// L3 in-wave reduce -> own 16 outputs. No __syncthreads anywhere.
// DS traffic/block ~96KB (vs 240KB e/c-sliced). LDS 32KB -> 4 blocks/CU.
__global__ __launch_bounds__(256, 4) void fused_mlp(
    const float* __restrict__ X,
    const float* __restrict__ b1, const float* __restrict__ b2,
    const float* __restrict__ W3, const float* __restrict__ b3,
    const u16* __restrict__ w1fr, const u16* __restrict__ w2fr,
    float* __restrict__ out)
{
    __shared__ __align__(16) u16 arena[4 * 4096];   // 32 KB: 8KB per wave
    const int tid = threadIdx.x;
    const int w   = tid >> 6;
    const int l   = tid & 63;
    const int lc  = l & 15;
    const int lk  = l >> 4;
    const int b   = blockIdx.x;
    const float* Xb = X + (size_t)b * 8192;

    u16* const W = arena + w * 4096;   // wave-private region (u16 units)

    // ---------- phase 0 (per-wave): X rows n=16w+lc -> xt_w[n'=lc][d], swizzled ----------
    // lane(lc,lk): d-chunks dc = lk+4i; element (n'=lc, d) chunk slot = dc^lc.
    #pragma unroll
    for (int i = 0; i < 4; ++i) {
        const int dc = lk + 4 * i, d0 = dc << 3;
        float v[8];
        #pragma unroll
        for (int j = 0; j < 8; ++j)
            v[j] = Xb[(d0 + j) * 64 + 16 * w + lc];   // 4 x 64B segments per j-instr
        u32 pk[4];
        #pragma unroll
        for (int j = 0; j < 4; ++j) pk[j] = pack2bf(v[2 * j], v[2 * j + 1]);
        *(uint4*)(W + lc * 128 + (((dc ^ lc) & 15) << 3)) = make_uint4(pk[0], pk[1], pk[2], pk[3]);
    }

    // ---------- layer 1: D1[c=0..255][n=16w+lc]; A=w1fr tile m, B=own xt row ----------
    f32x4 acc[16];
    #pragma unroll
    for (int m = 0; m < 16; ++m) acc[m] = (f32x4){0.f, 0.f, 0.f, 0.f};

    #pragma unroll
    for (int ks = 0; ks < 4; ++ks) {
        const bf16x8 bfr = *(const bf16x8*)(W + lc * 128 + ((((4 * ks + lk) ^ lc) & 15) << 3));
        #pragma unroll
        for (int m = 0; m < 16; ++m) {
            const bf16x8 afr = *(const bf16x8*)(w1fr + (m * 4 + ks) * 512 + l * 8);
            acc[m] = __builtin_amdgcn_mfma_f32_16x16x32_bf16(afr, bfr, acc[m], 0, 0, 0);
        }
    }

    // ---------- epilogue 1: +b1, relu, pack -> h1_w (same region; in-wave RAW only) ----------
    // lane(lc,lk) holds D1[c=16m+4lk+r][n=16w+lc]; write uint2 (4 c) at row lc.
    #pragma unroll
    for (int m = 0; m < 16; ++m) {
        const int c0 = 16 * m + 4 * lk;
        const float4 bq = *(const float4*)(b1 + c0);
        float x0 = fmaxf(acc[m][0] + bq.x, 0.f);
        float x1 = fmaxf(acc[m][1] + bq.y, 0.f);
        float x2 = fmaxf(acc[m][2] + bq.z, 0.f);
        float x3 = fmaxf(acc[m][3] + bq.w, 0.f);
        const int slot = ((c0 >> 3) ^ lc) & 31;        // (2m + (lk>>1)) ^ lc
        *(uint2*)(W + lc * 256 + (slot << 3) + (c0 & 7)) =
            make_uint2(pack2bf(x0, x1), pack2bf(x2, x3));
    }

    // ---------- layer 2: D2[n=16w+..][e=0..255]; A=own h1 row, B=w2fr tile t ----------
    f32x4 acc2[16];
    #pragma unroll
    for (int t = 0; t < 16; ++t) acc2[t] = (f32x4){0.f, 0.f, 0.f, 0.f};

    #pragma unroll
    for (int ks = 0; ks < 8; ++ks) {
        const bf16x8 afr = *(const bf16x8*)(W + lc * 256 + ((((4 * ks + lk) ^ lc) & 31) << 3));
        #pragma unroll
        for (int t = 0; t < 16; ++t) {
            const bf16x8 bfr = *(const bf16x8*)(w2fr + (t * 8 + ks) * 512 + l * 8);
            acc2[t] = __builtin_amdgcn_mfma_f32_16x16x32_bf16(afr, bfr, acc2[t], 0, 0, 0);
        }
    }

    // ---------- layer 3: +b2, relu, dot W3 over e, in-wave reduce, store own rows ----------
    // lane(lc,lk) holds D2[n=16w+4lk+r][e=16t+lc].
    float s0 = 0.f, s1 = 0.f, s2 = 0.f, s3 = 0.f;
    #pragma unroll
    for (int t = 0; t < 16; ++t) {
        const int e = 16 * t + lc;
        const float bv = b2[e];
        const float wv = W3[e];
        s0 += fmaxf(acc2[t][0] + bv, 0.f) * wv;
        s1 += fmaxf(acc2[t][1] + bv, 0.f) * wv;
        s2 += fmaxf(acc2[t][2] + bv, 0.f) * wv;
        s3 += fmaxf(acc2[t][3] + bv, 0.f) * wv;
    }
    float sr[4] = {s0, s1, s2, s3};
    #pragma unroll
    for (int r = 0; r < 4; ++r) {
        float s = sr[r];
        s += __shfl_xor(s, 1);
        s += __shfl_xor(s, 2);
        s += __shfl_xor(s, 4);
        s += __shfl_xor(s, 8);                        // sum over 16 e-lanes
        sr[r] = s;
    }
    if (lc == 0) {
        const float b3v = b3[0];
        const int n0 = 16 * w + 4 * lk;
        #pragma unroll
        for (int r = 0; r < 4; ++r)
            out[(size_t)b * 65 + 1 + n0 + r] = sr[r] + b3v;
    }
    if (tid == 0) out[(size_t)b * 65] = 0.f;          // add_zero column
}

extern "C" void kernel_launch(void* const* d_in, const int* in_sizes, int n_in,
                              void* d_out, int out_size, void* d_ws, size_t ws_size,
                              hipStream_t stream) {
    const float* X  = (const float*)d_in[0];
    const float* W1 = (const float*)d_in[1];
    const float* b1 = (const float*)d_in[2];
    const float* W2 = (const float*)d_in[3];
    const float* b2 = (const float*)d_in[4];
    const float* W3 = (const float*)d_in[5];
    const float* b3 = (const float*)d_in[6];
    float* out = (float*)d_out;

    u16* w1fr = (u16*)d_ws;            // 64 KB
    u16* w2fr = w1fr + 32768;          // 128 KB

    const int B = in_sizes[0] / (128 * 64);   // 8192

    prep_weights<<<384, 256, 0, stream>>>(W1, W2, w1fr, w2fr);
    fused_mlp<<<B, 256, 0, stream>>>(X, b1, b2, W3, b3, w1fr, w2fr, out);
}

// Round 16
// 158.914 us; speedup vs baseline: 2.5173x; 2.5173x over previous
//
#include <hip/hip_runtime.h>
#include <hip/hip_bf16.h>

typedef unsigned short u16;
typedef unsigned int   u32;
typedef __attribute__((ext_vector_type(8))) short bf16x8;
typedef __attribute__((ext_vector_type(4))) float f32x4;

#define NB 8192

__device__ __forceinline__ u32 pack2bf(float a, float b) {
    __hip_bfloat162 h = __float22bfloat162_rn(make_float2(a, b));  // v_cvt_pk_bf16_f32
    return *reinterpret_cast<u32*>(&h);
}

__device__ __forceinline__ u16 f2bf(float x) {
    u32 u = __float_as_uint(x);
    u32 r = u + 0x7FFFu + ((u >> 16) & 1u);
    return (u16)(r >> 16);
}

// Fragment-linear weight layouts (R7, proven): frag f = 512 elems in lane*8 order.
//   w1fr: f = (wv*4 + mt)*4 + ks    elem(l,j): W1[d][c], d=32ks+8*(l>>4)+j, c=64wv+16mt+(l&15)
//   w2fr: f = (wv*4 + et)*8 + ks    elem(l,j): W2[c][e], c=32ks+8*(l>>4)+j, e=64wv+16et+(l&15)
__global__ __launch_bounds__(256) void prep_weights(
    const float* __restrict__ W1, const float* __restrict__ W2,
    u16* __restrict__ w1fr, u16* __restrict__ w2fr)
{
    int tid = blockIdx.x * 256 + threadIdx.x;
    if (tid < 32768) {
        const int f = tid >> 9, r = tid & 511, l = r >> 3, j = r & 7;
        const int wv = f >> 4, mt = (f >> 2) & 3, ks = f & 3;
        const int c = 64 * wv + 16 * mt + (l & 15);
        const int d = 32 * ks + 8 * (l >> 4) + j;
        w1fr[tid] = f2bf(W1[d * 256 + c]);
    } else {
        const int t2 = tid - 32768;
        if (t2 < 65536) {
            const int f = t2 >> 9, r = t2 & 511, l = r >> 3, j = r & 7;
            const int wv = f >> 5, et = (f >> 3) & 3, ks = f & 7;
            const int e = 64 * wv + 16 * et + (l & 15);
            const int c = 32 * ks + 8 * (l >> 4) + j;
            w2fr[t2] = f2bf(W2[c * 256 + e]);
        }
    }
}

// R7 champion, byte-identical structure, + s_setprio(1) around the MFMA nests
// (T5: 4 independent blocks/CU with generation drift = phase-diverse waves;
// setprio biases the CU scheduler toward MFMA-phase waves).
// One block = one batch b: 64 nodes, 4 waves. 32KB LDS arena, disjoint-lifetime
// tenants: xt (16KB) -> h1s (32KB) -> partl (1KB). 4 blocks/CU.
__global__ __launch_bounds__(256, 4) void fused_mlp(
    const float* __restrict__ X,
    const float* __restrict__ b1, const float* __restrict__ b2,
    const float* __restrict__ W3, const float* __restrict__ b3,
    const u16* __restrict__ w1fr, const u16* __restrict__ w2fr,
    float* __restrict__ out)
{
    __shared__ u16 smem[64 * 256];    // 32 KB arena
    u16* xt   = smem;                 // bf16 XT[n][d], 16B-chunk XOR-swizzled by (n&15)
    u16* h1s  = smem;                 // bf16 h1[n][c], same swizzle
    float* partl = (float*)smem;      // [4][64]

    const int tid = threadIdx.x;
    const int w   = tid >> 6;
    const int l   = tid & 63;
    const int lc  = l & 15;
    const int lk  = l >> 4;
    const int b   = blockIdx.x;
    const float* Xb = X + (size_t)b * 8192;

    const u16* w1b = w1fr + w * 8192  + l * 8;   // per-wave frag base (elems)
    const u16* w2b = w2fr + w * 16384 + l * 8;

    // ---------- phase 0: X[b] (d-major) -> LDS XT[n][d] bf16 ----------
    #pragma unroll
    for (int it = 0; it < 4; ++it) {
        const int dc = w + 4 * it, d0 = dc << 3;
        float v[8];
        #pragma unroll
        for (int j = 0; j < 8; ++j) v[j] = Xb[(d0 + j) * 64 + l];   // coalesced per j
        u32 pk[4];
        #pragma unroll
        for (int j = 0; j < 4; ++j) pk[j] = pack2bf(v[2 * j], v[2 * j + 1]);
        *(uint4*)(xt + l * 128 + ((dc ^ lc) << 3)) = make_uint4(pk[0], pk[1], pk[2], pk[3]);
    }

    // hoist ks=0 A-frag loads above the barrier (contiguous 1KB each)
    bf16x8 afrN[4];
    #pragma unroll
    for (int mt = 0; mt < 4; ++mt)
        afrN[mt] = *(const bf16x8*)(w1b + mt * 2048);
    __syncthreads();                               // B0: xt valid

    // ---------- layer 1: D1[c][n] = sum_d W1T[c][d] * XT[n][d] ----------
    f32x4 acc[4][4];
    #pragma unroll
    for (int mt = 0; mt < 4; ++mt)
        #pragma unroll
        for (int nt = 0; nt < 4; ++nt) acc[mt][nt] = (f32x4){0.f, 0.f, 0.f, 0.f};

    #pragma unroll
    for (int ks = 0; ks < 4; ++ks) {
        bf16x8 afr[4], bfr[4];
        #pragma unroll
        for (int mt = 0; mt < 4; ++mt) afr[mt] = afrN[mt];
        if (ks < 3) {                              // 1-deep prefetch, contiguous 1KB
            #pragma unroll
            for (int mt = 0; mt < 4; ++mt)
                afrN[mt] = *(const bf16x8*)(w1b + (mt * 4 + ks + 1) * 512);
        }
        #pragma unroll
        for (int nt = 0; nt < 4; ++nt)
            bfr[nt] = *(const bf16x8*)(xt + (16 * nt + lc) * 128 + (((4 * ks + lk) ^ lc) << 3));
        __builtin_amdgcn_s_setprio(1);
        #pragma unroll
        for (int mt = 0; mt < 4; ++mt)
            #pragma unroll
            for (int nt = 0; nt < 4; ++nt)
                acc[mt][nt] = __builtin_amdgcn_mfma_f32_16x16x32_bf16(afr[mt], bfr[nt], acc[mt][nt], 0, 0, 0);
        __builtin_amdgcn_s_setprio(0);
    }
    __syncthreads();                               // B1: xt readers done before h1 overwrite

    // ---------- epilogue 1: +b1, relu, bf16 -> h1s ----------
    #pragma unroll
    for (int mt = 0; mt < 4; ++mt) {
        const int c0 = 64 * w + 16 * mt + 4 * lk;
        const float4 bv = *(const float4*)(b1 + c0);
        #pragma unroll
        for (int nt = 0; nt < 4; ++nt) {
            const int n = 16 * nt + lc;
            float x0 = fmaxf(acc[mt][nt][0] + bv.x, 0.f);
            float x1 = fmaxf(acc[mt][nt][1] + bv.y, 0.f);
            float x2 = fmaxf(acc[mt][nt][2] + bv.z, 0.f);
            float x3 = fmaxf(acc[mt][nt][3] + bv.w, 0.f);
            const int chunk = (c0 >> 3) ^ lc;
            *(uint2*)(h1s + n * 256 + (chunk << 3) + (c0 & 7)) =
                make_uint2(pack2bf(x0, x1), pack2bf(x2, x3));
        }
    }

    // hoist ks=0 B-frag loads above the barrier
    bf16x8 bfrN[4];
    #pragma unroll
    for (int nt = 0; nt < 4; ++nt)
        bfrN[nt] = *(const bf16x8*)(w2b + nt * 4096);
    __syncthreads();                               // B2: h1s visible

    // ---------- layer 2: D2[n][e] = sum_c h1[n][c] * W2T[e][c] ----------
    f32x4 acc2[4][4];
    #pragma unroll
    for (int mt = 0; mt < 4; ++mt)
        #pragma unroll
        for (int nt = 0; nt < 4; ++nt) acc2[mt][nt] = (f32x4){0.f, 0.f, 0.f, 0.f};

    #pragma unroll
    for (int ks = 0; ks < 8; ++ks) {
        bf16x8 afr[4], bfr[4];
        #pragma unroll
        for (int nt = 0; nt < 4; ++nt) bfr[nt] = bfrN[nt];
        if (ks < 7) {
            #pragma unroll
            for (int nt = 0; nt < 4; ++nt)
                bfrN[nt] = *(const bf16x8*)(w2b + (nt * 8 + ks + 1) * 512);
        }
        #pragma unroll
        for (int mt = 0; mt < 4; ++mt)
            afr[mt] = *(const bf16x8*)(h1s + (16 * mt + lc) * 256 + (((4 * ks + lk) ^ lc) << 3));
        __builtin_amdgcn_s_setprio(1);
        #pragma unroll
        for (int mt = 0; mt < 4; ++mt)
            #pragma unroll
            for (int nt = 0; nt < 4; ++nt)
                acc2[mt][nt] = __builtin_amdgcn_mfma_f32_16x16x32_bf16(afr[mt], bfr[nt], acc2[mt][nt], 0, 0, 0);
        __builtin_amdgcn_s_setprio(0);
    }
    __syncthreads();                               // B3: h1s readers done, partl may overwrite

    // ---------- layer 3: +b2, relu, dot W3, reduce over e ----------
    float b2v[4], w3v[4];
    #pragma unroll
    for (int nt = 0; nt < 4; ++nt) {
        const int e = 64 * w + 16 * nt + lc;
        b2v[nt] = b2[e];
        w3v[nt] = W3[e];
    }
    #pragma unroll
    for (int mt = 0; mt < 4; ++mt) {
        #pragma unroll
        for (int j = 0; j < 4; ++j) {              // row n = 16mt + 4lk + j
            float s = 0.f;
            #pragma unroll
            for (int nt = 0; nt < 4; ++nt)
                s += fmaxf(acc2[mt][nt][j] + b2v[nt], 0.f) * w3v[nt];
            s += __shfl_xor(s, 1);
            s += __shfl_xor(s, 2);
            s += __shfl_xor(s, 4);
            s += __shfl_xor(s, 8);                 // sum over 16 e-lanes
            if (lc == 0) partl[w * 64 + 16 * mt + 4 * lk + j] = s;
        }
    }
    __syncthreads();                               // B4: partl visible

    if (tid < 64) {
        float s = partl[0 * 64 + tid] + partl[1 * 64 + tid] + partl[2 * 64 + tid] + partl[3 * 64 + tid] + b3[0];
        out[(size_t)b * 65 + 1 + tid] = s;
    } else if (tid == 64) {
        out[(size_t)b * 65] = 0.f;                 // add_zero column
    }
}

extern "C" void kernel_launch(void* const* d_in, const int* in_sizes, int n_in,
                              void* d_out, int out_size, void* d_ws, size_t ws_size,
                              hipStream_t stream) {
    const float* X  = (const float*)d_in[0];
    const float* W1 = (const float*)d_in[1];
    const float* b1 = (const float*)d_in[2];
    const float* W2 = (const float*)d_in[3];
    const float* b2 = (const float*)d_in[4];
    const float* W3 = (const float*)d_in[5];
    const float* b3 = (const float*)d_in[6];
    float* out = (float*)d_out;

    u16* w1fr = (u16*)d_ws;            // 32768 elems = 64 KB
    u16* w2fr = w1fr + 32768;          // 65536 elems = 128 KB

    const int B = in_sizes[0] / (128 * 64);   // 8192

    prep_weights<<<384, 256, 0, stream>>>(W1, W2, w1fr, w2fr);
    fused_mlp<<<B, 256, 0, stream>>>(X, b1, b2, W3, b3, w1fr, w2fr, out);
}